// Round 2
// baseline (2413.564 us; speedup 1.0000x reference)
//
#include <hip/hip_runtime.h>

// VQ: x (16,64,64,64) f32, codebook e (64,1024) f32. N=65536, D=64, K=1024.
//
// R8: halve the per-CU L2-stream (the R7-identified shared bottleneck).
//  - 2-term scheme: scores approximated as (xh+xl)*eh only (el dropped).
//    B-frags store ONLY eh: 2 KB/tile (was 4), 4 MFMAs per (mt,tile) (was 6).
//  - Soundness: |d_np - d_apx| <= 2*Sum|x|*halfulp(e) + slop. Since
//    |e| < 0.25, halfulp <= 2^-11, so bound = 2^-10 * S1_p + slack.
//    Certify iff (m1 - m2) > E_p, E_p = 2^-10 * S1_p + 1.5e-3 where
//    S1_p = Sum_d |x_pd| (computed during A-build, shfl-reduced, via LDS).
//    Uncertified positions -> exact fallback overwrite (unchanged guarantee).
//  - Fallback restructured wave-per-position (was block-per-position with
//    8-barrier tree): 16 codes/lane (k = lane*16+m), d-outer FMA chains kept
//    bit-exact (sequential-d fmaf per code, pairwise-8 Ap, same tie-breaks).
//    ~2k cyc/position/wave, 4096 positions/round at grid 1024.

#define D 64
#define K 1024
#define NPOS 65536
#define HW 4096
#define XSTRIDE 262144  // D*HW

typedef float vfloat4 __attribute__((ext_vector_type(4)));
typedef short short8  __attribute__((ext_vector_type(8)));

static __device__ __forceinline__ unsigned short bf16_rne(float f) {
    unsigned u = __float_as_uint(f);
    u += 0x7FFFu + ((u >> 16) & 1u);
    return (unsigned short)(u >> 16);
}
static __device__ __forceinline__ float bf16_to_f32(unsigned short h) {
    return __uint_as_float(((unsigned)h) << 16);
}

// ---- prep: codebook -> bf16 HI-ONLY B-fragments + c2n = -0.5*sum(e^2) -----
// frag layout: ebf[tile][s][lane][j], lane=q*16+n, value = bf16(e[d][k]),
// d=s*32+q*8+j, k=tile*16+n. Lane l reads 16B at l*16 (coalesced b128).
// c2n[k] = -0.5 * (sequential-d sum of rounded squares); fallback's
// c2[k] = -2*c2n[k] is bit-identical to the verified prep_c2.
__global__ void vq_prep(const float* __restrict__ e,
                        unsigned short* __restrict__ ebf,
                        float* __restrict__ c2n,
                        int* __restrict__ wl_count) {
    const int tile = blockIdx.x;               // 0..63
    const int t = threadIdx.x;
    if (tile == 0 && t == 0) *wl_count = 0;    // ws re-poisoned every launch
    const int n = t & 15;
    const int dg = t >> 4;                     // 0..15
#pragma unroll
    for (int i = 0; i < 4; ++i) {
        const int d = dg * 4 + i;
        const float v = e[d * K + tile * 16 + n];
        const unsigned short hh = bf16_rne(v);
        const int s = d >> 5, q = (d >> 3) & 3, j = d & 7;
        const int lanei = q * 16 + n;
        ebf[((tile * 2 + s) * 64 + lanei) * 8 + j] = hh;
    }
    if (t < 16) {
        const int k = tile * 16 + t;
        float s = 0.f;
#pragma unroll
        for (int d = 0; d < D; ++d) {
            const float v = e[d * K + k];
            s = s + __fmul_rn(v, v);
        }
        c2n[k] = -0.5f * s;
    }
}

// ---- main: 1024 blocks x 256; block = 64 positions; wave = (pg, kh) -------
__global__ __launch_bounds__(256, 4)
void vq_main(const float* __restrict__ x, const float* __restrict__ e,
             const unsigned short* __restrict__ ebf,
             const float* __restrict__ c2n,
             float* __restrict__ out, int* __restrict__ wl_count,
             int* __restrict__ wl) {
    __shared__ int   bk_lds[64];
    __shared__ float ls1[2][32];
    __shared__ float ls2[2][32];
    __shared__ int   lk1[2][32];
    __shared__ float s1a_lds[2][32];           // Sum|x| per position
    const int t = threadIdx.x;
    const int lane = t & 63;
    const int w = t >> 6;
    const int pg = w & 1;                      // position group (32 each)
    const int kh = w >> 1;                     // k-half (32 tiles each)
    const int p0 = blockIdx.x * 64;
    const int b = p0 >> 12;
    const int sp0 = p0 & (HW - 1);
    const int n = lane & 15;                   // A-row m / B-col n / C col
    const int q = lane >> 4;                   // k-quad / C row group

    // A-frags (registers): xh/xl for 2 M-tiles x 2 K-steps; + Sum|x|/pos
    short8 ah[2][2], al[2][2];
#pragma unroll
    for (int mt = 0; mt < 2; ++mt) {
        const int spc = sp0 + pg * 32 + mt * 16 + n;
        float s1a = 0.f;
#pragma unroll
        for (int s = 0; s < 2; ++s) {
            short8 fh, fl_;
#pragma unroll
            for (int j = 0; j < 8; ++j) {
                const int d = s * 32 + q * 8 + j;      // A[m=n][k=q*8+j]
                const float v = x[(size_t)b * XSTRIDE + (size_t)d * HW + spc];
                const unsigned short h = bf16_rne(v);
                fh[j] = (short)h;
                fl_[j] = (short)bf16_rne(v - bf16_to_f32(h));
                s1a += fabsf(v);
            }
            ah[mt][s] = fh; al[mt][s] = fl_;
        }
        // reduce Sum|x| over q-groups (lanes n, n+16, n+32, n+48); butterfly
        // gives every lane the same bits (fp add is commutative bitwise).
        s1a += __shfl_xor(s1a, 16, 64);
        s1a += __shfl_xor(s1a, 32, 64);
        if (kh == 0 && q == 0) s1a_lds[pg][mt * 16 + n] = s1a;
    }

    const short8* ebv = (const short8*)ebf;
    float s1[2][4], s2[2][4]; int t1[2][4];
#pragma unroll
    for (int mt = 0; mt < 2; ++mt)
#pragma unroll
        for (int r = 0; r < 4; ++r) { s1[mt][r] = -3.4e38f; s2[mt][r] = -3.4e38f; t1[mt][r] = 0; }

    // pipelined loop over this wave's 32 k-tiles (no barriers, no exec churn)
    const int tbase = kh * 32;
    short8 bh0 = ebv[(tbase * 2 + 0) * 64 + lane];
    short8 bh1 = ebv[(tbase * 2 + 1) * 64 + lane];
    float c2v = c2n[tbase * 16 + n];
#pragma unroll 2
    for (int tt = 0; tt < 32; ++tt) {
        const int tile = tbase + tt;
        const int tn = (tt == 31) ? tbase : (tile + 1);  // uniform wrap
        const short8 nbh0 = ebv[(tn * 2 + 0) * 64 + lane];
        const short8 nbh1 = ebv[(tn * 2 + 1) * 64 + lane];
        const float nc2 = c2n[tn * 16 + n];
#pragma unroll
        for (int mt = 0; mt < 2; ++mt) {
            vfloat4 acc = {c2v, c2v, c2v, c2v};    // m = x.e_h - 0.5*c2
            acc = __builtin_amdgcn_mfma_f32_16x16x32_bf16(ah[mt][0], bh0, acc, 0, 0, 0);
            acc = __builtin_amdgcn_mfma_f32_16x16x32_bf16(ah[mt][1], bh1, acc, 0, 0, 0);
            acc = __builtin_amdgcn_mfma_f32_16x16x32_bf16(al[mt][0], bh0, acc, 0, 0, 0);
            acc = __builtin_amdgcn_mfma_f32_16x16x32_bf16(al[mt][1], bh1, acc, 0, 0, 0);
#pragma unroll
            for (int r = 0; r < 4; ++r) {      // C/D: row=q*4+r, col=n; argMAX
                const float m = acc[r];
                const bool gt = m > s1[mt][r];
                s2[mt][r] = fmaxf(s2[mt][r], fminf(m, s1[mt][r]));
                s1[mt][r] = gt ? m : s1[mt][r];
                t1[mt][r] = gt ? tile : t1[mt][r];
            }
        }
        bh0 = nbh0; bh1 = nbh1; c2v = nc2;
    }

    // merge top-2 across the 16 code-columns (lanes within a q-group)
#pragma unroll
    for (int mt = 0; mt < 2; ++mt)
#pragma unroll
        for (int r = 0; r < 4; ++r) {
            float a1 = s1[mt][r], a2 = s2[mt][r];
            int ak = t1[mt][r] * 16 + n;
#pragma unroll
            for (int m = 1; m < 16; m <<= 1) {
                const float o1 = __shfl_xor(a1, m, 64);
                const float o2 = __shfl_xor(a2, m, 64);
                const int   ok = __shfl_xor(ak, m, 64);
                const bool take = (o1 > a1) || (o1 == a1 && ok < ak);
                const float loser = take ? a1 : o1;
                a1 = take ? o1 : a1;
                ak = take ? ok : ak;
                a2 = fmaxf(fmaxf(a2, o2), loser);
            }
            s1[mt][r] = a1; s2[mt][r] = a2; t1[mt][r] = ak;  // ak is code idx
            if (kh == 1 && n == 0) {
                const int pos32 = mt * 16 + q * 4 + r;
                ls1[pg][pos32] = a1; ls2[pg][pos32] = a2; lk1[pg][pos32] = ak;
            }
        }
    __syncthreads();

    // kh==0 combines both K-halves, certifies with per-position margin
    if (kh == 0 && n == 0) {
#pragma unroll
        for (int mt = 0; mt < 2; ++mt)
#pragma unroll
            for (int r = 0; r < 4; ++r) {
                const int pos32 = mt * 16 + q * 4 + r;
                const float a1 = s1[mt][r], a2 = s2[mt][r];
                const int   ak = t1[mt][r];
                const float b1 = ls1[pg][pos32], b2 = ls2[pg][pos32];
                const int   bk2 = lk1[pg][pos32];
                const bool take = (b1 > a1) || (b1 == a1 && bk2 < ak);
                const float w1 = take ? b1 : a1;
                const int   wk = take ? bk2 : ak;
                const float w2 = fmaxf(fminf(a1, b1), fmaxf(a2, b2));
                bk_lds[pg * 32 + pos32] = wk;
                // E_p = 2^-10 * Sum|x| + slack  (el-drop bound + accum slop)
                const float Ep = 0.0009765625f * s1a_lds[pg][pos32] + 1.5e-3f;
                if (w1 - w2 <= Ep) {           // not certified -> exact redo
                    const int idx = atomicAdd(wl_count, 1);
                    wl[idx] = p0 + pg * 32 + pos32;
                }
            }
    }
    __syncthreads();

    // write all 64 positions x 64 channels (fallback overwrites ambiguous)
    const int pl = t & 63;
    const int cg = t >> 6;
    const int bk = bk_lds[pl];
    const int sp = sp0 + pl;
    const float* xb = x + (size_t)b * XSTRIDE + sp;
    float* ob = out + (size_t)b * XSTRIDE + sp;
#pragma unroll
    for (int i = 0; i < 16; ++i) {
        const int c = cg * 16 + i;
        const float xq = xb[(size_t)c * HW];
        const float qv = e[c * K + bk];
        ob[(size_t)c * HW] = xq + (qv - xq);   // np STE: fl(x + fl(q-x))
    }
}

// ---- fallback: bit-exact np scan, one position per WAVE -------------------
__global__ __launch_bounds__(256, 2)
void vq_fallback(const float* __restrict__ x, const float* __restrict__ e,
                 const float* __restrict__ c2n,
                 const int* __restrict__ wl_count, const int* __restrict__ wl,
                 float* __restrict__ out) {
    const int t = threadIdx.x;
    const int lane = t & 63;
    const int w = t >> 6;
    const int count = *wl_count;
    for (int i = blockIdx.x * 4 + w; i < count; i += gridDim.x * 4) {
        const int pos = wl[i];
        const int b = pos >> 12, sp = pos & (HW - 1);
        const float* xp = x + (size_t)b * XSTRIDE + sp;
        float xv[D];                           // broadcast loads, L1/L2-hot
#pragma unroll
        for (int d = 0; d < D; ++d) xv[d] = xp[(size_t)d * HW];
        // Ap = np.sum(x**2) in numpy pairwise-8 order (verified grouping)
        float r8[8];
#pragma unroll
        for (int i0 = 0; i0 < 8; ++i0) r8[i0] = __fmul_rn(xv[i0], xv[i0]);
#pragma unroll
        for (int j = 1; j < 8; ++j)
#pragma unroll
            for (int i0 = 0; i0 < 8; ++i0)
                r8[i0] = r8[i0] + __fmul_rn(xv[8 * j + i0], xv[8 * j + i0]);
        const float Ap = ((r8[0] + r8[1]) + (r8[2] + r8[3])) + ((r8[4] + r8[5]) + (r8[6] + r8[7]));
        // 16 codes per lane: k = lane*16 + m; sequential-d FMA chain per code
        float acc[16];
#pragma unroll
        for (int m = 0; m < 16; ++m) acc[m] = 0.f;
#pragma unroll
        for (int d = 0; d < D; ++d) {
            const float xd = xv[d];
            const vfloat4 e0 = *(const vfloat4*)(e + d * K + lane * 16);
            const vfloat4 e1 = *(const vfloat4*)(e + d * K + lane * 16 + 4);
            const vfloat4 e2 = *(const vfloat4*)(e + d * K + lane * 16 + 8);
            const vfloat4 e3 = *(const vfloat4*)(e + d * K + lane * 16 + 12);
#pragma unroll
            for (int c = 0; c < 4; ++c) {
                acc[c]      = __builtin_fmaf(xd, e0[c], acc[c]);
                acc[4 + c]  = __builtin_fmaf(xd, e1[c], acc[4 + c]);
                acc[8 + c]  = __builtin_fmaf(xd, e2[c], acc[8 + c]);
                acc[12 + c] = __builtin_fmaf(xd, e3[c], acc[12 + c]);
            }
        }
        float bs = 3.4e38f; int bk = 0x7fffffff;
#pragma unroll
        for (int m = 0; m < 16; ++m) {
            const int k = lane * 16 + m;       // ascending k per lane
            const float c2k = -2.0f * c2n[k];  // exact pow2 scale = np c2[k]
            const float sc = __builtin_fmaf(-2.f, acc[m], Ap) + c2k;
            if (sc < bs || (sc == bs && k < bk)) { bs = sc; bk = k; }
        }
        // wave butterfly argmin; lane-major k order matches global k order
#pragma unroll
        for (int mm = 1; mm < 64; mm <<= 1) {
            const float os = __shfl_xor(bs, mm, 64);
            const int   ok = __shfl_xor(bk, mm, 64);
            if (os < bs || (os == bs && ok < bk)) { bs = os; bk = ok; }
        }
        // write 64 channels, lane = channel (bk uniform across wave)
        const float xq = xp[(size_t)lane * HW];
        const float qv = e[lane * K + bk];
        out[(size_t)b * XSTRIDE + (size_t)lane * HW + sp] = xq + (qv - xq);
    }
}

extern "C" void kernel_launch(void* const* d_in, const int* in_sizes, int n_in,
                              void* d_out, int out_size, void* d_ws, size_t ws_size,
                              hipStream_t stream) {
    const float* x = (const float*)d_in[0];
    const float* e = (const float*)d_in[1];
    float* out = (float*)d_out;

    char* ws = (char*)d_ws;                          // ~391 KB used
    unsigned short* ebf = (unsigned short*)ws;       // 128 KB B-fragments (hi only)
    float* c2n = (float*)(ws + 131072);              // 4 KB  (-0.5*sum e^2)
    int* wl_count = (int*)(ws + 135168);             // 16 B
    int* wl = (int*)(ws + 135184);                   // 256 KB worklist

    vq_prep<<<64, 256, 0, stream>>>(e, ebf, c2n, wl_count);
    vq_main<<<NPOS / 64, 256, 0, stream>>>(x, e, ebf, c2n, out, wl_count, wl);
    vq_fallback<<<1024, 256, 0, stream>>>(x, e, c2n, wl_count, wl, out);
}

// Round 3
// 446.683 us; speedup vs baseline: 5.4033x; 5.4033x over previous
//
#include <hip/hip_runtime.h>

// VQ: x (16,64,64,64) f32, codebook e (64,1024) f32. N=65536, D=64, K=1024.
//
// R9: revert R8's 2-term margin (blew up the worklist); attack vq_main's real
// bottleneck identified by R6==R7 invariance: per-CU L2->L1 fill on the
// private ebf streams (512 MB total at ~16 B/cyc/CU ~= 53 us).
//  - vq_main: 256 blocks x 512 threads (1 block/CU), block = 256 positions,
//    8 waves x 2 M-tiles. The 4 KB/tile bf16-split B-fragments are staged
//    ONCE per block into double-buffered LDS via global_load_lds (width 16,
//    linear dest = wave-uniform base + lane*16, per-lane global src); all 8
//    waves ds_read_b128 from LDS. L2 traffic 512 MB -> 64 MB (8x).
//    One barrier per tile; stage for t+1 issued at loop top (overlap).
//  - Scheme = R7-verified 3-term split-bf16 (x=xh+xl, e=eh+el; xh*eh + xl*eh
//    + xh*el), m = x.e - 0.5*c2 tracked via acc init, argMAX, certify iff
//    m1-m2 > MARGIN/2 (score gap = 2*(m1-m2)); else exact-fallback overwrite.
//  - fallback: R8-verified wave-per-position bit-exact np scan, now 2
//    positions per wave (halves its per-position 256 KB e-stream) with
//    shfl-broadcast x rows (no LDS, no registers blowup).

#define D 64
#define K 1024
#define NPOS 65536
#define HW 4096
#define XSTRIDE 262144  // D*HW
#define MARGIN 1.0e-3f

typedef float vfloat4 __attribute__((ext_vector_type(4)));
typedef short short8  __attribute__((ext_vector_type(8)));
#define AS1 __attribute__((address_space(1)))
#define AS3 __attribute__((address_space(3)))

static __device__ __forceinline__ unsigned short bf16_rne(float f) {
    unsigned u = __float_as_uint(f);
    u += 0x7FFFu + ((u >> 16) & 1u);
    return (unsigned short)(u >> 16);
}
static __device__ __forceinline__ float bf16_to_f32(unsigned short h) {
    return __uint_as_float(((unsigned)h) << 16);
}

// ---- prep: codebook -> bf16 split B-fragments + c2n = -0.5*sum(e^2) -------
// frag layout: ebf[tile][s][split][lane][j], lane=q*16+n, value =
// split(e[d][k]), d=s*32+q*8+j, k=tile*16+n. Lane l owns 16B at l*16, so the
// main kernel's global_load_lds (linear dest) and ds_read_b128 match exactly.
__global__ void vq_prep(const float* __restrict__ e,
                        unsigned short* __restrict__ ebf,
                        float* __restrict__ c2n,
                        int* __restrict__ wl_count) {
    const int tile = blockIdx.x;               // 0..63
    const int t = threadIdx.x;
    if (tile == 0 && t == 0) *wl_count = 0;    // ws re-poisoned every launch
    const int n = t & 15;
    const int dg = t >> 4;                     // 0..15
#pragma unroll
    for (int i = 0; i < 4; ++i) {
        const int d = dg * 4 + i;
        const float v = e[d * K + tile * 16 + n];
        const unsigned short hh = bf16_rne(v);
        const float rem = v - bf16_to_f32(hh);     // exact (Sterbenz)
        const unsigned short hl = bf16_rne(rem);
        const int s = d >> 5, q = (d >> 3) & 3, j = d & 7;
        const int lanei = q * 16 + n;
        ebf[(((tile * 2 + s) * 2 + 0) * 64 + lanei) * 8 + j] = hh;
        ebf[(((tile * 2 + s) * 2 + 1) * 64 + lanei) * 8 + j] = hl;
    }
    if (t < 16) {
        const int k = tile * 16 + t;
        float s = 0.f;
#pragma unroll
        for (int d = 0; d < D; ++d) {
            const float v = e[d * K + k];      // sequential-d rounded squares
            s = s + __fmul_rn(v, v);
        }
        c2n[k] = -0.5f * s;
    }
}

// ---- main: 256 blocks x 512 threads; block = 256 positions, 8 waves -------
__global__ __launch_bounds__(512, 2)
void vq_main(const float* __restrict__ x, const float* __restrict__ e,
             const unsigned short* __restrict__ ebf,
             const float* __restrict__ c2n,
             float* __restrict__ out, int* __restrict__ wl_count,
             int* __restrict__ wl) {
    __shared__ __align__(16) unsigned short lds_e[2][2048];  // 2 x 4 KB tiles
    __shared__ int bk_lds[256];
    const int t = threadIdx.x;
    const int lane = t & 63;
    const int w = t >> 6;                      // wave 0..7 = position group
    const int p0 = blockIdx.x * 256;
    const int b = p0 >> 12;                    // 256 | 4096 -> single b
    const int sp0 = p0 & (HW - 1);
    const int n = lane & 15;                   // A-row m / B-col n / C col
    const int q = lane >> 4;                   // k-quad / C row group

    // A-frags (registers): xh/xl for 2 M-tiles x 2 K-steps
    short8 ah[2][2], al[2][2];
#pragma unroll
    for (int mt = 0; mt < 2; ++mt) {
        const int spc = sp0 + w * 32 + mt * 16 + n;
#pragma unroll
        for (int s = 0; s < 2; ++s) {
            short8 fh, fl_;
#pragma unroll
            for (int j = 0; j < 8; ++j) {
                const int d = s * 32 + q * 8 + j;      // A[m=n][k=q*8+j]
                const float v = x[(size_t)b * XSTRIDE + (size_t)d * HW + spc];
                const unsigned short h = bf16_rne(v);
                fh[j] = (short)h;
                fl_[j] = (short)bf16_rne(v - bf16_to_f32(h));
            }
            ah[mt][s] = fh; al[mt][s] = fl_;
        }
    }

    // stage tile 0 into buf 0 (waves 0..3, 1 KB each, linear LDS dest)
    if (w < 4) {
        const unsigned short* g = ebf + (size_t)0 * 2048 + w * 512 + lane * 8;
        __builtin_amdgcn_global_load_lds((const AS1 unsigned int*)g,
                                         (AS3 unsigned int*)(&lds_e[0][w * 512]),
                                         16, 0, 0);
    }

    float s1[2][4], s2[2][4]; int t1[2][4];
#pragma unroll
    for (int mt = 0; mt < 2; ++mt)
#pragma unroll
        for (int r = 0; r < 4; ++r) { s1[mt][r] = -3.4e38f; s2[mt][r] = -3.4e38f; t1[mt][r] = 0; }

    __syncthreads();                           // tile 0 staged (full drain)

    for (int tt = 0; tt < 64; ++tt) {
        const int cur = tt & 1;
        if (w < 4 && tt < 63) {                // stage t+1 early: overlap L2
            const unsigned short* g = ebf + (size_t)(tt + 1) * 2048 + w * 512 + lane * 8;
            __builtin_amdgcn_global_load_lds((const AS1 unsigned int*)g,
                                             (AS3 unsigned int*)(&lds_e[cur ^ 1][w * 512]),
                                             16, 0, 0);
        }
        const short8* fb = (const short8*)(&lds_e[cur][0]);
        const short8 bh0 = fb[lane];           // s0 hi
        const short8 bl0 = fb[64 + lane];      // s0 lo
        const short8 bh1 = fb[128 + lane];     // s1 hi
        const short8 bl1 = fb[192 + lane];     // s1 lo
        const float c2v = c2n[tt * 16 + n];
#pragma unroll
        for (int mt = 0; mt < 2; ++mt) {
            vfloat4 acc = {c2v, c2v, c2v, c2v};    // m = x.e - 0.5*c2
            acc = __builtin_amdgcn_mfma_f32_16x16x32_bf16(ah[mt][0], bh0, acc, 0, 0, 0);
            acc = __builtin_amdgcn_mfma_f32_16x16x32_bf16(ah[mt][1], bh1, acc, 0, 0, 0);
            acc = __builtin_amdgcn_mfma_f32_16x16x32_bf16(al[mt][0], bh0, acc, 0, 0, 0);
            acc = __builtin_amdgcn_mfma_f32_16x16x32_bf16(al[mt][1], bh1, acc, 0, 0, 0);
            acc = __builtin_amdgcn_mfma_f32_16x16x32_bf16(ah[mt][0], bl0, acc, 0, 0, 0);
            acc = __builtin_amdgcn_mfma_f32_16x16x32_bf16(ah[mt][1], bl1, acc, 0, 0, 0);
#pragma unroll
            for (int r = 0; r < 4; ++r) {      // C/D: row=q*4+r, col=n; argMAX
                const float m = acc[r];
                const bool gt = m > s1[mt][r];
                s2[mt][r] = fmaxf(s2[mt][r], fminf(m, s1[mt][r]));
                s1[mt][r] = gt ? m : s1[mt][r];
                t1[mt][r] = gt ? tt : t1[mt][r];
            }
        }
        __syncthreads();                       // drains stage vmcnt + LDS reads
    }

    // merge top-2 across the 16 code-columns; certify; record; push worklist
#pragma unroll
    for (int mt = 0; mt < 2; ++mt)
#pragma unroll
        for (int r = 0; r < 4; ++r) {
            float a1 = s1[mt][r], a2 = s2[mt][r];
            int ak = t1[mt][r] * 16 + n;
#pragma unroll
            for (int m = 1; m < 16; m <<= 1) {
                const float o1 = __shfl_xor(a1, m, 64);
                const float o2 = __shfl_xor(a2, m, 64);
                const int   ok = __shfl_xor(ak, m, 64);
                const bool take = (o1 > a1) || (o1 == a1 && ok < ak);
                const float loser = take ? a1 : o1;
                a1 = take ? o1 : a1;
                ak = take ? ok : ak;
                a2 = fmaxf(fmaxf(a2, o2), loser);
            }
            if (n == 0) {
                const int pl = w * 32 + mt * 16 + q * 4 + r;
                bk_lds[pl] = ak;
                if (a1 - a2 <= 0.5f * MARGIN) {   // score gap = 2*(m1-m2)
                    const int idx = atomicAdd(wl_count, 1);
                    wl[idx] = p0 + pl;
                }
            }
        }
    __syncthreads();

    // write all 256 positions x 64 channels (fallback overwrites ambiguous)
    const int pl = t & 255;
    const int cg = t >> 8;                     // 0/1 -> 32 channels each
    const int bk = bk_lds[pl];
    const int sp = sp0 + pl;
    const float* xb = x + (size_t)b * XSTRIDE + sp;
    float* ob = out + (size_t)b * XSTRIDE + sp;
#pragma unroll
    for (int i = 0; i < 32; ++i) {
        const int c = cg * 32 + i;
        const float xq = xb[(size_t)c * HW];
        const float qv = e[c * K + bk];
        ob[(size_t)c * HW] = xq + (qv - xq);   // np STE: fl(x + fl(q-x))
    }
}

// ---- fallback: bit-exact np scan, TWO positions per wave ------------------
__global__ __launch_bounds__(256, 2)
void vq_fallback(const float* __restrict__ x, const float* __restrict__ e,
                 const float* __restrict__ c2n,
                 const int* __restrict__ wl_count, const int* __restrict__ wl,
                 float* __restrict__ out) {
    const int t = threadIdx.x;
    const int lane = t & 63;
    const int w = t >> 6;
    const int count = *wl_count;
    for (int ip = blockIdx.x * 4 + w; 2 * ip < count; ip += gridDim.x * 4) {
        const int iA = 2 * ip, iB = iA + 1;
        const bool hasB = iB < count;
        const int posA = wl[iA];
        const int posB = hasB ? wl[iB] : posA;
        const int bA = posA >> 12, spA = posA & (HW - 1);
        const int bB = posB >> 12, spB = posB & (HW - 1);
        // lane holds channel d=lane of each position; broadcast via shfl
        const float myA = x[(size_t)bA * XSTRIDE + (size_t)lane * HW + spA];
        const float myB = x[(size_t)bB * XSTRIDE + (size_t)lane * HW + spB];
        // Ap = np.sum(x**2) in numpy pairwise-8 order (verified grouping)
        float r8a[8], r8b[8];
#pragma unroll
        for (int i0 = 0; i0 < 8; ++i0) {
            const float va = __shfl(myA, i0, 64);
            const float vb = __shfl(myB, i0, 64);
            r8a[i0] = __fmul_rn(va, va);
            r8b[i0] = __fmul_rn(vb, vb);
        }
#pragma unroll
        for (int j = 1; j < 8; ++j)
#pragma unroll
            for (int i0 = 0; i0 < 8; ++i0) {
                const float va = __shfl(myA, 8 * j + i0, 64);
                const float vb = __shfl(myB, 8 * j + i0, 64);
                r8a[i0] = r8a[i0] + __fmul_rn(va, va);
                r8b[i0] = r8b[i0] + __fmul_rn(vb, vb);
            }
        const float ApA = ((r8a[0] + r8a[1]) + (r8a[2] + r8a[3])) + ((r8a[4] + r8a[5]) + (r8a[6] + r8a[7]));
        const float ApB = ((r8b[0] + r8b[1]) + (r8b[2] + r8b[3])) + ((r8b[4] + r8b[5]) + (r8b[6] + r8b[7]));
        // 16 codes per lane (k = lane*16+m); sequential-d FMA chain per code;
        // ONE shared e-stream serves both positions.
        float accA[16], accB[16];
#pragma unroll
        for (int m = 0; m < 16; ++m) { accA[m] = 0.f; accB[m] = 0.f; }
#pragma unroll
        for (int d = 0; d < D; ++d) {
            const float xdA = __shfl(myA, d, 64);
            const float xdB = __shfl(myB, d, 64);
            const vfloat4 e0 = *(const vfloat4*)(e + d * K + lane * 16);
            const vfloat4 e1 = *(const vfloat4*)(e + d * K + lane * 16 + 4);
            const vfloat4 e2 = *(const vfloat4*)(e + d * K + lane * 16 + 8);
            const vfloat4 e3 = *(const vfloat4*)(e + d * K + lane * 16 + 12);
#pragma unroll
            for (int c = 0; c < 4; ++c) {
                accA[c]      = __builtin_fmaf(xdA, e0[c], accA[c]);
                accA[4 + c]  = __builtin_fmaf(xdA, e1[c], accA[4 + c]);
                accA[8 + c]  = __builtin_fmaf(xdA, e2[c], accA[8 + c]);
                accA[12 + c] = __builtin_fmaf(xdA, e3[c], accA[12 + c]);
                accB[c]      = __builtin_fmaf(xdB, e0[c], accB[c]);
                accB[4 + c]  = __builtin_fmaf(xdB, e1[c], accB[4 + c]);
                accB[8 + c]  = __builtin_fmaf(xdB, e2[c], accB[8 + c]);
                accB[12 + c] = __builtin_fmaf(xdB, e3[c], accB[12 + c]);
            }
        }
        float bsA = 3.4e38f, bsB = 3.4e38f; int bkA = 0x7fffffff, bkB = 0x7fffffff;
#pragma unroll
        for (int m = 0; m < 16; ++m) {
            const int k = lane * 16 + m;       // ascending k per lane
            const float c2k = -2.0f * c2n[k];  // exact pow2 scale = np c2[k]
            const float scA = __builtin_fmaf(-2.f, accA[m], ApA) + c2k;
            const float scB = __builtin_fmaf(-2.f, accB[m], ApB) + c2k;
            if (scA < bsA || (scA == bsA && k < bkA)) { bsA = scA; bkA = k; }
            if (scB < bsB || (scB == bsB && k < bkB)) { bsB = scB; bkB = k; }
        }
#pragma unroll
        for (int mm = 1; mm < 64; mm <<= 1) {  // lane-major k order = global
            const float oa = __shfl_xor(bsA, mm, 64);
            const int   ka = __shfl_xor(bkA, mm, 64);
            if (oa < bsA || (oa == bsA && ka < bkA)) { bsA = oa; bkA = ka; }
            const float ob = __shfl_xor(bsB, mm, 64);
            const int   kb = __shfl_xor(bkB, mm, 64);
            if (ob < bsB || (ob == bsB && kb < bkB)) { bsB = ob; bkB = kb; }
        }
        // write 64 channels, lane = channel (bk uniform across wave)
        {
            const float qv = e[lane * K + bkA];
            out[(size_t)bA * XSTRIDE + (size_t)lane * HW + spA] = myA + (qv - myA);
        }
        if (hasB) {
            const float qv = e[lane * K + bkB];
            out[(size_t)bB * XSTRIDE + (size_t)lane * HW + spB] = myB + (qv - myB);
        }
    }
}

extern "C" void kernel_launch(void* const* d_in, const int* in_sizes, int n_in,
                              void* d_out, int out_size, void* d_ws, size_t ws_size,
                              hipStream_t stream) {
    const float* x = (const float*)d_in[0];
    const float* e = (const float*)d_in[1];
    float* out = (float*)d_out;

    char* ws = (char*)d_ws;                          // ~517 KB used
    unsigned short* ebf = (unsigned short*)ws;       // 256 KB B-fragments
    float* c2n = (float*)(ws + 262144);              // 4 KB  (-0.5*sum e^2)
    int* wl_count = (int*)(ws + 266240);             // 16 B
    int* wl = (int*)(ws + 266256);                   // 256 KB worklist

    vq_prep<<<64, 256, 0, stream>>>(e, ebf, c2n, wl_count);
    vq_main<<<NPOS / 256, 512, 0, stream>>>(x, e, ebf, c2n, out, wl_count, wl);
    vq_fallback<<<512, 256, 0, stream>>>(x, e, c2n, wl_count, wl, out);
}

// Round 4
// 131.235 us; speedup vs baseline: 18.3912x; 3.4037x over previous
//
#include <hip/hip_runtime.h>

// VQ: x (16,64,64,64) f32, codebook e (64,1024) f32. N=65536, D=64, K=1024.
//
// R10: post-mortem of R9: fallback WRITE_SIZE=17.4MB == full output => the
// main kernel's certificate rejected ~ALL positions. Only-new-element was the
// global_load_lds double-buffer (stale-tile reads make top1==top2 => reject
// all). Fix: REGISTER-staged LDS double-buffer (global->VGPR->ds_write_b128),
// where every ordering is a compiler-enforced data dependency:
//   loop top: stg = global_load(tile tt+1)        (latency hidden under work)
//   compute:  ds_read buf[cur] -> 6 MFMA x 2 mt -> top-2
//   loop end: ds_write buf[cur^1] = stg; __syncthreads()  (lgkmcnt drained)
// Block = 256 thr / 128 positions / 4 waves sharing each 4KB tile: per-CU L2
// stream 2MB -> 512KB (the R6==R7 invariance showed this stream is the
// bottleneck). 2 blocks/CU for overlap.
// Scheme (proven in R6/R7, absmax 0, ~97% certified): 3-term split-bf16
// (xh*eh + xl*eh + xh*el), m = x.e - 0.5*c2 via acc-init, argMAX, certify iff
// m1-m2 > MARGIN/2; fallback = R7-verbatim block-per-position bit-exact np
// scan (register-cached x, pairwise-8 Ap, sequential-k FMA chain).

#define D 64
#define K 1024
#define NPOS 65536
#define HW 4096
#define XSTRIDE 262144  // D*HW
#define MARGIN 1.0e-3f

typedef float vfloat4 __attribute__((ext_vector_type(4)));
typedef short short8  __attribute__((ext_vector_type(8)));

static __device__ __forceinline__ unsigned short bf16_rne(float f) {
    unsigned u = __float_as_uint(f);
    u += 0x7FFFu + ((u >> 16) & 1u);
    return (unsigned short)(u >> 16);
}
static __device__ __forceinline__ float bf16_to_f32(unsigned short h) {
    return __uint_as_float(((unsigned)h) << 16);
}

// ---- prep: codebook -> bf16 split B-fragments + c2n = -0.5*sum(e^2) -------
// frag layout: ebf[tile][s][split][lane][j], lane=q*16+n, value =
// split(e[d][k]), d=s*32+q*8+j, k=tile*16+n. Thread t of the main kernel
// owns 16B at t*16 within a tile: stage load + ds_write are linear copies.
__global__ void vq_prep(const float* __restrict__ e,
                        unsigned short* __restrict__ ebf,
                        float* __restrict__ c2n,
                        int* __restrict__ wl_count) {
    const int tile = blockIdx.x;               // 0..63
    const int t = threadIdx.x;
    if (tile == 0 && t == 0) *wl_count = 0;    // ws re-poisoned every launch
    const int n = t & 15;
    const int dg = t >> 4;                     // 0..15
#pragma unroll
    for (int i = 0; i < 4; ++i) {
        const int d = dg * 4 + i;
        const float v = e[d * K + tile * 16 + n];
        const unsigned short hh = bf16_rne(v);
        const float rem = v - bf16_to_f32(hh);     // exact (Sterbenz)
        const unsigned short hl = bf16_rne(rem);
        const int s = d >> 5, q = (d >> 3) & 3, j = d & 7;
        const int lanei = q * 16 + n;
        ebf[(((tile * 2 + s) * 2 + 0) * 64 + lanei) * 8 + j] = hh;
        ebf[(((tile * 2 + s) * 2 + 1) * 64 + lanei) * 8 + j] = hl;
    }
    if (t < 16) {
        const int k = tile * 16 + t;
        float s = 0.f;
#pragma unroll
        for (int d = 0; d < D; ++d) {
            const float v = e[d * K + k];      // sequential-d rounded squares
            s = s + __fmul_rn(v, v);
        }
        c2n[k] = -0.5f * s;
    }
}

// ---- main: 512 blocks x 256 threads; block = 128 positions, 4 waves -------
__global__ __launch_bounds__(256, 2)
void vq_main(const float* __restrict__ x, const float* __restrict__ e,
             const unsigned short* __restrict__ ebf,
             const float* __restrict__ c2n,
             float* __restrict__ out, int* __restrict__ wl_count,
             int* __restrict__ wl) {
    __shared__ __align__(16) unsigned short lds_e[2][2048];  // 2 x 4 KB tiles
    __shared__ int bk_lds[128];
    const int t = threadIdx.x;
    const int lane = t & 63;
    const int w = t >> 6;                      // wave 0..3 = position group
    const int p0 = blockIdx.x * 128;
    const int b = p0 >> 12;                    // 128 | 4096 -> single b
    const int sp0 = p0 & (HW - 1);
    const int n = lane & 15;                   // A-row m / B-col n / C col
    const int q = lane >> 4;                   // k-quad / C row group

    // A-frags (registers): xh/xl for 2 M-tiles x 2 K-steps
    short8 ah[2][2], al[2][2];
#pragma unroll
    for (int mt = 0; mt < 2; ++mt) {
        const int spc = sp0 + w * 32 + mt * 16 + n;
#pragma unroll
        for (int s = 0; s < 2; ++s) {
            short8 fh, fl_;
#pragma unroll
            for (int j = 0; j < 8; ++j) {
                const int d = s * 32 + q * 8 + j;      // A[m=n][k=q*8+j]
                const float v = x[(size_t)b * XSTRIDE + (size_t)d * HW + spc];
                const unsigned short h = bf16_rne(v);
                fh[j] = (short)h;
                fl_[j] = (short)bf16_rne(v - bf16_to_f32(h));
            }
            ah[mt][s] = fh; al[mt][s] = fl_;
        }
    }

    // stage tile 0: global -> reg -> LDS (thread t owns 16B at t*16)
    {
        const short8 stg = *(const short8*)(ebf + t * 8);
        *(short8*)(&lds_e[0][t * 8]) = stg;
    }

    float s1[2][4], s2[2][4]; int t1[2][4];
#pragma unroll
    for (int mt = 0; mt < 2; ++mt)
#pragma unroll
        for (int r = 0; r < 4; ++r) { s1[mt][r] = -3.4e38f; s2[mt][r] = -3.4e38f; t1[mt][r] = 0; }

    __syncthreads();                           // tile 0 in LDS (lgkmcnt drain)

    for (int tt = 0; tt < 64; ++tt) {
        const int cur = tt & 1;
        short8 stg;
        if (tt < 63)                           // issue early: hide L2 latency
            stg = *(const short8*)(ebf + (size_t)(tt + 1) * 2048 + t * 8);
        const short8* fb = (const short8*)(&lds_e[cur][0]);
        const short8 bh0 = fb[lane];           // s0 hi
        const short8 bl0 = fb[64 + lane];      // s0 lo
        const short8 bh1 = fb[128 + lane];     // s1 hi
        const short8 bl1 = fb[192 + lane];     // s1 lo
        const float c2v = c2n[tt * 16 + n];
#pragma unroll
        for (int mt = 0; mt < 2; ++mt) {
            vfloat4 acc = {c2v, c2v, c2v, c2v};    // m = x.e - 0.5*c2
            acc = __builtin_amdgcn_mfma_f32_16x16x32_bf16(ah[mt][0], bh0, acc, 0, 0, 0);
            acc = __builtin_amdgcn_mfma_f32_16x16x32_bf16(ah[mt][1], bh1, acc, 0, 0, 0);
            acc = __builtin_amdgcn_mfma_f32_16x16x32_bf16(al[mt][0], bh0, acc, 0, 0, 0);
            acc = __builtin_amdgcn_mfma_f32_16x16x32_bf16(al[mt][1], bh1, acc, 0, 0, 0);
            acc = __builtin_amdgcn_mfma_f32_16x16x32_bf16(ah[mt][0], bl0, acc, 0, 0, 0);
            acc = __builtin_amdgcn_mfma_f32_16x16x32_bf16(ah[mt][1], bl1, acc, 0, 0, 0);
#pragma unroll
            for (int r = 0; r < 4; ++r) {      // C/D: row=q*4+r, col=n; argMAX
                const float m = acc[r];
                const bool gt = m > s1[mt][r];
                s2[mt][r] = fmaxf(s2[mt][r], fminf(m, s1[mt][r]));
                s1[mt][r] = gt ? m : s1[mt][r];
                t1[mt][r] = gt ? tt : t1[mt][r];
            }
        }
        if (tt < 63)                           // reg dep forces vmcnt wait
            *(short8*)(&lds_e[cur ^ 1][t * 8]) = stg;
        __syncthreads();                       // ds_write visible to all waves
    }

    // merge top-2 across the 16 code-columns; certify; record; push worklist
#pragma unroll
    for (int mt = 0; mt < 2; ++mt)
#pragma unroll
        for (int r = 0; r < 4; ++r) {
            float a1 = s1[mt][r], a2 = s2[mt][r];
            int ak = t1[mt][r] * 16 + n;
#pragma unroll
            for (int m = 1; m < 16; m <<= 1) {
                const float o1 = __shfl_xor(a1, m, 64);
                const float o2 = __shfl_xor(a2, m, 64);
                const int   ok = __shfl_xor(ak, m, 64);
                const bool take = (o1 > a1) || (o1 == a1 && ok < ak);
                const float loser = take ? a1 : o1;
                a1 = take ? o1 : a1;
                ak = take ? ok : ak;
                a2 = fmaxf(fmaxf(a2, o2), loser);
            }
            if (n == 0) {
                const int pl = w * 32 + mt * 16 + q * 4 + r;
                bk_lds[pl] = ak;
                if (a1 - a2 <= 0.5f * MARGIN) {   // score gap = 2*(m1-m2)
                    const int idx = atomicAdd(wl_count, 1);
                    wl[idx] = p0 + pl;
                }
            }
        }
    __syncthreads();

    // write all 128 positions x 64 channels (fallback overwrites ambiguous)
    const int pl = t & 127;
    const int half = t >> 7;
    const int bk = bk_lds[pl];
    const int sp = sp0 + pl;
    const float* xb = x + (size_t)b * XSTRIDE + sp;
    float* ob = out + (size_t)b * XSTRIDE + sp;
#pragma unroll
    for (int i = 0; i < 32; ++i) {
        const int c = half * 32 + i;
        const float xq = xb[(size_t)c * HW];
        const float qv = e[c * K + bk];
        ob[(size_t)c * HW] = xq + (qv - xq);   // np STE: fl(x + fl(q-x))
    }
}

// ---- fallback: bit-exact np scan, block-per-position (R7-verbatim) --------
__global__ __launch_bounds__(256, 2)
void vq_fallback(const float* __restrict__ x, const float* __restrict__ e,
                 const float* __restrict__ c2n,
                 const int* __restrict__ wl_count, const int* __restrict__ wl,
                 float* __restrict__ out) {
    __shared__ float rs[256];
    __shared__ int   rk[256];
    const int t = threadIdx.x;
    const int count = *wl_count;
    for (int i = blockIdx.x; i < count; i += gridDim.x) {
        const int pos = wl[i];
        const int b = pos >> 12, sp = pos & (HW - 1);
        float xv[D];                           // register-cache x (broadcast)
#pragma unroll
        for (int d = 0; d < D; ++d)
            xv[d] = x[(size_t)b * XSTRIDE + (size_t)d * HW + sp];
        // Ap = np.sum(x**2) in numpy pairwise-8 order (verified grouping)
        float r8[8];
#pragma unroll
        for (int i0 = 0; i0 < 8; ++i0) r8[i0] = __fmul_rn(xv[i0], xv[i0]);
#pragma unroll
        for (int j = 1; j < 8; ++j)
#pragma unroll
            for (int i0 = 0; i0 < 8; ++i0)
                r8[i0] = r8[i0] + __fmul_rn(xv[8 * j + i0], xv[8 * j + i0]);
        const float Ap = ((r8[0] + r8[1]) + (r8[2] + r8[3])) + ((r8[4] + r8[5]) + (r8[6] + r8[7]));
        float bs = 3.4e38f; int bk = 0x7fffffff;
#pragma unroll
        for (int j = 0; j < 4; ++j) {
            const int k = t + 256 * j;         // ascending k per thread
            float acc = 0.f;
#pragma unroll
            for (int d = 0; d < D; ++d)        // sequential-k FMA chain (np)
                acc = __builtin_fmaf(xv[d], e[d * K + k], acc);
            const float c2k = -2.0f * c2n[k];  // exact pow2 scale = np c2[k]
            const float sc = __builtin_fmaf(-2.f, acc, Ap) + c2k;
            if (sc < bs || (sc == bs && k < bk)) { bs = sc; bk = k; }
        }
        rs[t] = bs; rk[t] = bk;
        __syncthreads();
        for (int off = 128; off > 0; off >>= 1) {
            if (t < off) {
                const float so = rs[t + off]; const int ko = rk[t + off];
                if (so < rs[t] || (so == rs[t] && ko < rk[t])) { rs[t] = so; rk[t] = ko; }
            }
            __syncthreads();
        }
        const int kb = rk[0];
        if (t < 64) {
            const float xq = x[(size_t)b * XSTRIDE + (size_t)t * HW + sp];
            const float qv = e[t * K + kb];
            out[(size_t)b * XSTRIDE + (size_t)t * HW + sp] = xq + (qv - xq);
        }
        __syncthreads();
    }
}

extern "C" void kernel_launch(void* const* d_in, const int* in_sizes, int n_in,
                              void* d_out, int out_size, void* d_ws, size_t ws_size,
                              hipStream_t stream) {
    const float* x = (const float*)d_in[0];
    const float* e = (const float*)d_in[1];
    float* out = (float*)d_out;

    char* ws = (char*)d_ws;                          // ~517 KB used
    unsigned short* ebf = (unsigned short*)ws;       // 256 KB B-fragments
    float* c2n = (float*)(ws + 262144);              // 4 KB  (-0.5*sum e^2)
    int* wl_count = (int*)(ws + 266240);             // 16 B
    int* wl = (int*)(ws + 266256);                   // 256 KB worklist

    vq_prep<<<64, 256, 0, stream>>>(e, ebf, c2n, wl_count);
    vq_main<<<NPOS / 128, 256, 0, stream>>>(x, e, ebf, c2n, out, wl_count, wl);
    vq_fallback<<<1024, 256, 0, stream>>>(x, e, c2n, wl_count, wl, out);
}